// Round 12
// baseline (40.785 us; speedup 1.0000x reference)
//
#include <hip/hip_runtime.h>

// YOLO loss: N=4096, S=14, B=2, NC=20. ncells = 802816 = 1568 blocks * 512.
// R12: per-wave DOUBLE-REGION pipeline with counted vmcnt (no barriers).
// Each wave: 4 rounds x 64 cells, two private 7.68KB LDS regions ping-pong;
// one global_load_lds stage always in flight under compute. Conditional
// tcls gathers are issued BEFORE the next stage so FIFO-vmcnt waits for
// tcls (vmcnt(9)) keep the newest stage outstanding. BLOCK=128, 30.7KB LDS
// -> 5 blocks/CU. Ending = R6-proven 64-slot atomics + separate finalize.
// Proven-bad: block-barrier staging (R3-R5), conditional pred loads (R7),
// 2-pass split (R8), threadfence fused ending (R9), single-region pipe (R11).

#define GS 14
#define NCLS 20
#define BLOCK 128
#define WAVES 2
#define ROUNDS 4
#define WCELLS 64
#define CPW (ROUNDS * WCELLS)     // 256 cells per wave
#define CPB (WAVES * CPW)         // 512 cells per block
#define NSLOTS 64
#define SLOT_STRIDE 16            // floats = 64 B
#define WAVE_F 1920               // 64 cells * 30 floats
#define SLAB_F (WAVES * 2 * WAVE_F)  // 7680 floats = 30720 B

#define SB() __builtin_amdgcn_sched_barrier(0)

// ws layout (floats): slots at ws[s*16 + k], s in [0,64), k in [0,4)
// k: 0=reg, 1=cont, 2=noobj, 3=cls. Zeroed by hipMemsetAsync each call.

__device__ __forceinline__ void gload_lds16(const float* g, float* l) {
    __builtin_amdgcn_global_load_lds(
        (const __attribute__((address_space(1))) void*)g,
        (__attribute__((address_space(3))) void*)l, 16, 0, 0);
}
__device__ __forceinline__ void gload_lds4(const float* g, float* l) {
    __builtin_amdgcn_global_load_lds(
        (const __attribute__((address_space(1))) void*)g,
        (__attribute__((address_space(3))) void*)l, 4, 0, 0);
}

// 9 DMA ops = one 64-cell round (7680 B)
__device__ __forceinline__ void stage_wave(const float* gsrc, float* ldst, int lane) {
    #pragma unroll
    for (int i = 0; i < 7; ++i)                       // 7 x 1KB (width 16)
        gload_lds16(gsrc + i * 256 + lane * 4, ldst + i * 256);
    #pragma unroll
    for (int k = 0; k < 2; ++k)                       // tail 512B (width 4)
        gload_lds4(gsrc + 1792 + k * 64 + lane, ldst + 1792 + k * 64);
}

__device__ __forceinline__ void ds_read_row(const float* lrow, float (&v)[30]) {
    #pragma unroll
    for (int j = 0; j < 7; ++j)
        *reinterpret_cast<float4*>(&v[j * 4]) =
            *reinterpret_cast<const float4*>(lrow + j * 4);
    *reinterpret_cast<float2*>(&v[28]) =
        *reinterpret_cast<const float2*>(lrow + 28);
}

__device__ __forceinline__ void load_tc(const float* __restrict__ tcls, int cell, bool m,
                                        float4& t0, float4& t1, float4& t2,
                                        float4& t3, float4& t4) {
    t0 = t1 = t2 = t3 = t4 = make_float4(0.f, 0.f, 0.f, 0.f);
    if (m) {
        const float4* tp = reinterpret_cast<const float4*>(tcls) + (size_t)cell * 5;
        t0 = tp[0]; t1 = tp[1]; t2 = tp[2]; t3 = tp[3]; t4 = tp[4];
    }
}

__device__ __forceinline__ void cell_compute(const float (&v)[30],
                                             const float4 tb4,
                                             const float4 t0, const float4 t1,
                                             const float4 t2, const float4 t3,
                                             const float4 t4,
                                             bool m,
                                             float& reg, float& cont,
                                             float& noobj, float& cls) {
    const float invS = 1.0f / (float)GS;
    if (m) {
        const float tx = tb4.x, ty = tb4.y, tw = tb4.z, th = tb4.w;

        const float tcx = tx * invS, tcy = ty * invS;
        const float t_x1 = tcx - 0.5f * tw, t_y1 = tcy - 0.5f * th;
        const float t_x2 = tcx + 0.5f * tw, t_y2 = tcy + 0.5f * th;
        const float ta = (t_x2 - t_x1) * (t_y2 - t_y1);

        const float b0x = v[0], b0y = v[1], b0w = v[2], b0h = v[3], b0c = v[4];
        const float b1x = v[5], b1y = v[6], b1w = v[7], b1h = v[8], b1c = v[9];

        float iou0, iou1;
        {
            const float cx = b0x * invS, cy = b0y * invS;
            const float x1 = cx - 0.5f * b0w, y1 = cy - 0.5f * b0h;
            const float x2 = cx + 0.5f * b0w, y2 = cy + 0.5f * b0h;
            const float iw = fmaxf(fminf(x2, t_x2) - fmaxf(x1, t_x1), 0.0f);
            const float ih = fmaxf(fminf(y2, t_y2) - fmaxf(y1, t_y1), 0.0f);
            const float inter = iw * ih;
            const float pa = (x2 - x1) * (y2 - y1);
            iou0 = inter / (pa + ta - inter);
        }
        {
            const float cx = b1x * invS, cy = b1y * invS;
            const float x1 = cx - 0.5f * b1w, y1 = cy - 0.5f * b1h;
            const float x2 = cx + 0.5f * b1w, y2 = cy + 0.5f * b1h;
            const float iw = fmaxf(fminf(x2, t_x2) - fmaxf(x1, t_x1), 0.0f);
            const float ih = fmaxf(fminf(y2, t_y2) - fmaxf(y1, t_y1), 0.0f);
            const float inter = iw * ih;
            const float pa = (x2 - x1) * (y2 - y1);
            iou1 = inter / (pa + ta - inter);
        }

        const bool sel1 = iou1 > iou0;   // jnp.argmax: first max wins -> strict >
        const float biou = fmaxf(iou0, iou1);
        const float rx = sel1 ? b1x : b0x;
        const float ry = sel1 ? b1y : b0y;
        const float rw = sel1 ? b1w : b0w;
        const float rh = sel1 ? b1h : b0h;
        const float rc = sel1 ? b1c : b0c;

        const float d0 = rx - tx, d1 = ry - ty;
        const float d2 = sqrtf(rw) - sqrtf(tw);
        const float d3 = sqrtf(rh) - sqrtf(th);
        reg += d0 * d0 + d1 * d1 + d2 * d2 + d3 * d3;

        const float dc = rc - biou;
        cont += dc * dc;

        float csum = 0.0f;
        float d;
        d = v[10] - t0.x; csum += d * d;  d = v[11] - t0.y; csum += d * d;
        d = v[12] - t0.z; csum += d * d;  d = v[13] - t0.w; csum += d * d;
        d = v[14] - t1.x; csum += d * d;  d = v[15] - t1.y; csum += d * d;
        d = v[16] - t1.z; csum += d * d;  d = v[17] - t1.w; csum += d * d;
        d = v[18] - t2.x; csum += d * d;  d = v[19] - t2.y; csum += d * d;
        d = v[20] - t2.z; csum += d * d;  d = v[21] - t2.w; csum += d * d;
        d = v[22] - t3.x; csum += d * d;  d = v[23] - t3.y; csum += d * d;
        d = v[24] - t3.z; csum += d * d;  d = v[25] - t3.w; csum += d * d;
        d = v[26] - t4.x; csum += d * d;  d = v[27] - t4.y; csum += d * d;
        d = v[28] - t4.z; csum += d * d;  d = v[29] - t4.w; csum += d * d;
        cls += csum;
    } else {
        const float c0 = v[4], c1 = v[9];
        noobj += c0 * c0 + c1 * c1;
    }
}

__launch_bounds__(BLOCK)
__global__ void yolo_loss_kernel(const float* __restrict__ pred,
                                 const float* __restrict__ tbox,
                                 const float* __restrict__ tcls,
                                 const void* __restrict__ mask,
                                 float* __restrict__ ws,
                                 int ncells) {
    __shared__ float slab[SLAB_F];   // 30720 B: 2 waves x 2 regions x 1920 floats
    const int tid = threadIdx.x;
    const int wv = tid >> 6;
    const int lane = tid & 63;

    // ---- per-block mask-dtype sniff on the first 2KB (one barrier) ----
    //   fmt=0: int32, fmt=1: uint8/bool, fmt=2: float32
    int my_bits = 0;
    if (ncells >= 2048) {
        const uint4 w4 = reinterpret_cast<const uint4*>(mask)[tid];
        const unsigned a = w4.x | w4.y | w4.z | w4.w;
        my_bits  = ((a & 0xFEFEFEFEu) != 0) ? 2 : 0;
        my_bits |= ((a & 0xFFFFFF00u) != 0) ? 1 : 0;
    } else if (tid == 0) {
        const unsigned char* mb = (const unsigned char*)mask;
        for (int i = 0; i < ncells; ++i) {
            if (mb[i] > 1) my_bits |= 2;
            if ((i & 3) != 0 && mb[i] != 0) my_bits |= 1;
        }
    }
    const int bits = __syncthreads_or(my_bits);
    const int fmt = (bits & 2) ? 2 : ((bits & 1) ? 1 : 0);

    const int base = blockIdx.x * CPB;

    float reg = 0.0f, cont = 0.0f, noobj = 0.0f, cls = 0.0f;

    if (base + CPB <= ncells) {
        const int wbase = base + wv * CPW;
        const int ca = wbase + lane;
        const int cb = ca + 64, cc = ca + 128, cd = ca + 192;

        const float* gsrc = pred + (size_t)wbase * 30;
        float* R0 = slab + (wv * 2 + 0) * WAVE_F;
        float* R1 = slab + (wv * 2 + 1) * WAVE_F;
        const float* rowA = R0 + lane * 30;
        const float* rowB = R1 + lane * 30;

        // S0 -> R0
        stage_wave(gsrc, R0, lane);
        SB();

        // scalar loads for all 4 rounds, BEFORE S1 (so vmcnt(9) drains them)
        bool mA, mB, mC, mD;
        if (fmt == 2) {
            const float* mp = (const float*)mask;
            mA = mp[ca] != 0.0f; mB = mp[cb] != 0.0f;
            mC = mp[cc] != 0.0f; mD = mp[cd] != 0.0f;
        } else if (fmt == 1) {
            const unsigned char* mp = (const unsigned char*)mask;
            mA = mp[ca] != 0; mB = mp[cb] != 0;
            mC = mp[cc] != 0; mD = mp[cd] != 0;
        } else {
            const int* mp = (const int*)mask;
            mA = mp[ca] != 0; mB = mp[cb] != 0;
            mC = mp[cc] != 0; mD = mp[cd] != 0;
        }
        const float4* tbp = reinterpret_cast<const float4*>(tbox);
        const float4 tbA = tbp[ca], tbB = tbp[cb], tbC = tbp[cc], tbD = tbp[cd];
        SB();

        // S1 -> R1
        stage_wave(gsrc + WAVE_F, R1, lane);
        SB();

        // ---- round 0 (R0) ----
        {
            asm volatile("s_waitcnt vmcnt(9)" ::: "memory"); SB();  // S0 landed
            float v[30]; ds_read_row(rowA, v);
            asm volatile("s_waitcnt lgkmcnt(0)" ::: "memory"); SB();
            float4 t0, t1, t2, t3, t4;
            load_tc(tcls, ca, mA, t0, t1, t2, t3, t4); SB();        // before S2!
            stage_wave(gsrc + 2 * WAVE_F, R0, lane); SB();          // S2 -> R0
            cell_compute(v, tbA, t0, t1, t2, t3, t4, mA, reg, cont, noobj, cls);
        }
        // ---- round 1 (R1) ----
        {
            asm volatile("s_waitcnt vmcnt(9)" ::: "memory"); SB();  // S1 landed
            float v[30]; ds_read_row(rowB, v);
            asm volatile("s_waitcnt lgkmcnt(0)" ::: "memory"); SB();
            float4 t0, t1, t2, t3, t4;
            load_tc(tcls, cb, mB, t0, t1, t2, t3, t4); SB();        // before S3!
            stage_wave(gsrc + 3 * WAVE_F, R1, lane); SB();          // S3 -> R1
            cell_compute(v, tbB, t0, t1, t2, t3, t4, mB, reg, cont, noobj, cls);
        }
        // ---- round 2 (R0) ----
        {
            asm volatile("s_waitcnt vmcnt(9)" ::: "memory"); SB();  // S2 landed
            float v[30]; ds_read_row(rowA, v);
            float4 t0, t1, t2, t3, t4;
            load_tc(tcls, cc, mC, t0, t1, t2, t3, t4); SB();
            cell_compute(v, tbC, t0, t1, t2, t3, t4, mC, reg, cont, noobj, cls);
        }
        // ---- round 3 (R1) ----
        {
            asm volatile("s_waitcnt vmcnt(0)" ::: "memory"); SB();  // S3 landed
            float v[30]; ds_read_row(rowB, v);
            float4 t0, t1, t2, t3, t4;
            load_tc(tcls, cd, mD, t0, t1, t2, t3, t4);
            cell_compute(v, tbD, t0, t1, t2, t3, t4, mD, reg, cont, noobj, cls);
        }
    } else {
        // generic scalar tail (not hit when ncells % 512 == 0)
        for (int cell = base + tid; cell < ncells; cell += BLOCK) {
            bool m;
            if (fmt == 2)      m = ((const float*)mask)[cell] != 0.0f;
            else if (fmt == 1) m = ((const unsigned char*)mask)[cell] != 0;
            else               m = ((const int*)mask)[cell] != 0;
            float v[30];
            #pragma unroll
            for (int f = 0; f < 30; ++f) v[f] = pred[(size_t)cell * 30 + f];
            float4 tb;
            tb.x = tbox[(size_t)cell * 4 + 0];
            tb.y = tbox[(size_t)cell * 4 + 1];
            tb.z = tbox[(size_t)cell * 4 + 2];
            tb.w = tbox[(size_t)cell * 4 + 3];
            float4 t0, t1, t2, t3, t4;
            load_tc(tcls, cell, m, t0, t1, t2, t3, t4);
            cell_compute(v, tb, t0, t1, t2, t3, t4, m, reg, cont, noobj, cls);
        }
    }

    // ---- wave64 + block reduce (R6-proven ending) ----
    #pragma unroll
    for (int off = 32; off > 0; off >>= 1) {
        reg   += __shfl_down(reg, off);
        cont  += __shfl_down(cont, off);
        noobj += __shfl_down(noobj, off);
        cls   += __shfl_down(cls, off);
    }

    __shared__ float sred[WAVES][4];
    if (lane == 0) {
        sred[wv][0] = reg; sred[wv][1] = cont;
        sred[wv][2] = noobj; sred[wv][3] = cls;
    }
    __syncthreads();
    if (tid == 0) {
        float r = 0, c = 0, no = 0, cl = 0;
        #pragma unroll
        for (int w = 0; w < WAVES; ++w) {
            r += sred[w][0]; c += sred[w][1]; no += sred[w][2]; cl += sred[w][3];
        }
        float* slot = ws + (size_t)(blockIdx.x & (NSLOTS - 1)) * SLOT_STRIDE;
        atomicAdd(&slot[0], r);
        atomicAdd(&slot[1], c);
        atomicAdd(&slot[2], no);
        atomicAdd(&slot[3], cl);
    }
}

__global__ void yolo_finalize_kernel(const float* __restrict__ ws,
                                     float* __restrict__ out, float inv_n) {
    const int t = threadIdx.x;   // one wave: thread t owns slot t
    float reg   = ws[t * SLOT_STRIDE + 0];
    float cont  = ws[t * SLOT_STRIDE + 1];
    float noobj = ws[t * SLOT_STRIDE + 2];
    float cls   = ws[t * SLOT_STRIDE + 3];
    #pragma unroll
    for (int off = 32; off > 0; off >>= 1) {
        reg   += __shfl_down(reg, off);
        cont  += __shfl_down(cont, off);
        noobj += __shfl_down(noobj, off);
        cls   += __shfl_down(cls, off);
    }
    if (t == 0) {
        const float total = (5.0f * reg + 0.5f * noobj + cont + cls) * inv_n;
        out[0] = total;
        out[1] = reg;
        out[2] = cont;
        out[3] = noobj;
        out[4] = cls;
    }
}

extern "C" void kernel_launch(void* const* d_in, const int* in_sizes, int n_in,
                              void* d_out, int out_size, void* d_ws, size_t ws_size,
                              hipStream_t stream) {
    const float* pred = (const float*)d_in[0];
    const float* tbox = (const float*)d_in[1];
    const float* tcls = (const float*)d_in[2];
    const void*  mask = d_in[3];
    float* ws  = (float*)d_ws;
    float* out = (float*)d_out;

    const int ncells = in_sizes[3];                 // N * S * S
    const int n_img  = ncells / (GS * GS);          // N
    const float inv_n = 1.0f / (float)n_img;

    hipMemsetAsync(ws, 0, NSLOTS * SLOT_STRIDE * sizeof(float), stream);

    const int grid = (ncells + CPB - 1) / CPB;      // 1568
    yolo_loss_kernel<<<grid, BLOCK, 0, stream>>>(pred, tbox, tcls, mask, ws, ncells);

    yolo_finalize_kernel<<<1, 64, 0, stream>>>(ws, out, inv_n);
}

// Round 13
// 29.800 us; speedup vs baseline: 1.3686x; 1.3686x over previous
//
#include <hip/hip_runtime.h>

// YOLO loss: N=4096, S=14, B=2, NC=20. ncells = 802816 = 1568 blocks * 512.
// R13 = R11 body byte-for-byte (33.3 us best: per-wave global_load_lds
// staging, 2-round in-wave pipeline, wave-local vmcnt, no block barriers)
// + plain-store per-block slots (R7/R9-proven stores) + separate finalize
// reading all slots (kernel boundary = ordering). NO memset dispatch:
// graph is 2 dispatches instead of 3.
// Proven-bad: block-barrier staging (R3-R5), conditional pred loads (R7),
// 2-pass split (R8), in-kernel threadfence ending (R9), double-region
// counted-vmcnt pipeline (R12).

#define GS 14
#define NCLS 20
#define BLOCK 256
#define CPB 512             // cells per block (2 rounds x 64 cells/wave)
#define WAVE_F 1920         // floats per wave region (64 cells * 30)
#define SLAB_F (4 * WAVE_F) // 30720 B

// ws layout: ws[b*4 + k] = block b's partials {reg, cont, noobj, cls},
// plain float4 stores -- no zeroing needed, every slot written each call.

__device__ __forceinline__ void gload_lds16(const float* g, float* l) {
    __builtin_amdgcn_global_load_lds(
        (const __attribute__((address_space(1))) void*)g,
        (__attribute__((address_space(3))) void*)l, 16, 0, 0);
}
__device__ __forceinline__ void gload_lds4(const float* g, float* l) {
    __builtin_amdgcn_global_load_lds(
        (const __attribute__((address_space(1))) void*)g,
        (__attribute__((address_space(3))) void*)l, 4, 0, 0);
}

__device__ __forceinline__ void stage_wave(const float* gsrc, float* ldst, int lane) {
    #pragma unroll
    for (int i = 0; i < 7; ++i)                       // 7 x 1KB (width 16)
        gload_lds16(gsrc + i * 256 + lane * 4, ldst + i * 256);
    #pragma unroll
    for (int k = 0; k < 2; ++k)                       // tail 512B (width 4)
        gload_lds4(gsrc + 1792 + k * 64 + lane, ldst + 1792 + k * 64);
}

__device__ __forceinline__ void cell_compute(const float (&v)[30],
                                             const float4 tb4,
                                             const float* __restrict__ tcls,
                                             int cell, bool m,
                                             float& reg, float& cont,
                                             float& noobj, float& cls) {
    const float invS = 1.0f / (float)GS;
    if (m) {
        const float tx = tb4.x, ty = tb4.y, tw = tb4.z, th = tb4.w;

        const float tcx = tx * invS, tcy = ty * invS;
        const float t_x1 = tcx - 0.5f * tw, t_y1 = tcy - 0.5f * th;
        const float t_x2 = tcx + 0.5f * tw, t_y2 = tcy + 0.5f * th;
        const float ta = (t_x2 - t_x1) * (t_y2 - t_y1);

        const float b0x = v[0], b0y = v[1], b0w = v[2], b0h = v[3], b0c = v[4];
        const float b1x = v[5], b1y = v[6], b1w = v[7], b1h = v[8], b1c = v[9];

        float iou0, iou1;
        {
            const float cx = b0x * invS, cy = b0y * invS;
            const float x1 = cx - 0.5f * b0w, y1 = cy - 0.5f * b0h;
            const float x2 = cx + 0.5f * b0w, y2 = cy + 0.5f * b0h;
            const float iw = fmaxf(fminf(x2, t_x2) - fmaxf(x1, t_x1), 0.0f);
            const float ih = fmaxf(fminf(y2, t_y2) - fmaxf(y1, t_y1), 0.0f);
            const float inter = iw * ih;
            const float pa = (x2 - x1) * (y2 - y1);
            iou0 = inter / (pa + ta - inter);
        }
        {
            const float cx = b1x * invS, cy = b1y * invS;
            const float x1 = cx - 0.5f * b1w, y1 = cy - 0.5f * b1h;
            const float x2 = cx + 0.5f * b1w, y2 = cy + 0.5f * b1h;
            const float iw = fmaxf(fminf(x2, t_x2) - fmaxf(x1, t_x1), 0.0f);
            const float ih = fmaxf(fminf(y2, t_y2) - fmaxf(y1, t_y1), 0.0f);
            const float inter = iw * ih;
            const float pa = (x2 - x1) * (y2 - y1);
            iou1 = inter / (pa + ta - inter);
        }

        const bool sel1 = iou1 > iou0;   // jnp.argmax: first max wins -> strict >
        const float biou = fmaxf(iou0, iou1);
        const float rx = sel1 ? b1x : b0x;
        const float ry = sel1 ? b1y : b0y;
        const float rw = sel1 ? b1w : b0w;
        const float rh = sel1 ? b1h : b0h;
        const float rc = sel1 ? b1c : b0c;

        const float d0 = rx - tx, d1 = ry - ty;
        const float d2 = sqrtf(rw) - sqrtf(tw);
        const float d3 = sqrtf(rh) - sqrtf(th);
        reg += d0 * d0 + d1 * d1 + d2 * d2 + d3 * d3;

        const float dc = rc - biou;
        cont += dc * dc;

        const float4* tc4 = reinterpret_cast<const float4*>(tcls + (size_t)cell * NCLS);
        float csum = 0.0f;
        #pragma unroll
        for (int j = 0; j < 5; ++j) {
            const float4 t4 = tc4[j];
            float d;
            d = v[10 + j * 4 + 0] - t4.x; csum += d * d;
            d = v[10 + j * 4 + 1] - t4.y; csum += d * d;
            d = v[10 + j * 4 + 2] - t4.z; csum += d * d;
            d = v[10 + j * 4 + 3] - t4.w; csum += d * d;
        }
        cls += csum;
    } else {
        const float c0 = v[4], c1 = v[9];
        noobj += c0 * c0 + c1 * c1;
    }
}

__device__ __forceinline__ void ds_read_row(const float* lrow, float (&v)[30]) {
    #pragma unroll
    for (int j = 0; j < 7; ++j)
        *reinterpret_cast<float4*>(&v[j * 4]) =
            *reinterpret_cast<const float4*>(lrow + j * 4);
    *reinterpret_cast<float2*>(&v[28]) =
        *reinterpret_cast<const float2*>(lrow + 28);
}

__launch_bounds__(BLOCK)
__global__ void yolo_loss_kernel(const float* __restrict__ pred,
                                 const float* __restrict__ tbox,
                                 const float* __restrict__ tcls,
                                 const void* __restrict__ mask,
                                 float* __restrict__ ws,
                                 int ncells) {
    __shared__ float slab[SLAB_F];   // 30720 B: 4 waves x 1920 floats
    const int tid = threadIdx.x;
    const int wv = tid >> 6;
    const int lane = tid & 63;

    // ---- per-block mask-dtype sniff on the first 4KB (one barrier) ----
    //   fmt=0: int32, fmt=1: uint8/bool, fmt=2: float32
    int my_bits = 0;
    if (ncells >= 4096) {
        const uint4 w4 = reinterpret_cast<const uint4*>(mask)[tid];
        const unsigned a = w4.x | w4.y | w4.z | w4.w;
        my_bits  = ((a & 0xFEFEFEFEu) != 0) ? 2 : 0;
        my_bits |= ((a & 0xFFFFFF00u) != 0) ? 1 : 0;
    } else if (tid == 0) {
        const unsigned char* mb = (const unsigned char*)mask;
        for (int i = 0; i < ncells; ++i) {
            if (mb[i] > 1) my_bits |= 2;
            if ((i & 3) != 0 && mb[i] != 0) my_bits |= 1;
        }
    }
    const int bits = __syncthreads_or(my_bits);
    const int fmt = (bits & 2) ? 2 : ((bits & 1) ? 1 : 0);

    const int base = blockIdx.x * CPB;

    float reg = 0.0f, cont = 0.0f, noobj = 0.0f, cls = 0.0f;

    if (base + CPB <= ncells) {
        const int cellA = base + wv * 64 + lane;
        const int cellB = cellA + 256;

        const float* gsrcA = pred + (size_t)(base + wv * 64) * 30;
        const float* gsrcB = gsrcA + 256 * 30;
        float* ldst = slab + wv * WAVE_F;
        const float* lrow = ldst + lane * 30;

        // ---- stage A; scalar loads for BOTH rounds ride in its shadow ----
        stage_wave(gsrcA, ldst, lane);

        bool mA, mB;
        if (fmt == 2) {
            mA = ((const float*)mask)[cellA] != 0.0f;
            mB = ((const float*)mask)[cellB] != 0.0f;
        } else if (fmt == 1) {
            mA = ((const unsigned char*)mask)[cellA] != 0;
            mB = ((const unsigned char*)mask)[cellB] != 0;
        } else {
            mA = ((const int*)mask)[cellA] != 0;
            mB = ((const int*)mask)[cellB] != 0;
        }
        const float4 tbA = reinterpret_cast<const float4*>(tbox)[cellA];
        const float4 tbB = reinterpret_cast<const float4*>(tbox)[cellB];

        // ---- A landed (wave-local wait; other waves keep running) ----
        asm volatile("s_waitcnt vmcnt(0)" ::: "memory");
        __builtin_amdgcn_sched_barrier(0);

        float vA[30];
        ds_read_row(lrow, vA);

        // A's LDS reads must drain before B's DMA may overwrite the region
        asm volatile("s_waitcnt lgkmcnt(0)" ::: "memory");
        __builtin_amdgcn_sched_barrier(0);

        // ---- stage B; compute A hides its latency ----
        stage_wave(gsrcB, ldst, lane);

        cell_compute(vA, tbA, tcls, cellA, mA, reg, cont, noobj, cls);

        // ---- B landed ----
        asm volatile("s_waitcnt vmcnt(0)" ::: "memory");
        __builtin_amdgcn_sched_barrier(0);

        float vB[30];
        ds_read_row(lrow, vB);

        cell_compute(vB, tbB, tcls, cellB, mB, reg, cont, noobj, cls);
    } else {
        // generic scalar tail (not hit when ncells % 512 == 0)
        for (int cell = base + tid; cell < ncells; cell += BLOCK) {
            bool m;
            if (fmt == 2)      m = ((const float*)mask)[cell] != 0.0f;
            else if (fmt == 1) m = ((const unsigned char*)mask)[cell] != 0;
            else               m = ((const int*)mask)[cell] != 0;
            float v[30];
            #pragma unroll
            for (int f = 0; f < 30; ++f) v[f] = pred[(size_t)cell * 30 + f];
            float4 tb;
            tb.x = tbox[(size_t)cell * 4 + 0];
            tb.y = tbox[(size_t)cell * 4 + 1];
            tb.z = tbox[(size_t)cell * 4 + 2];
            tb.w = tbox[(size_t)cell * 4 + 3];
            cell_compute(v, tb, tcls, cell, m, reg, cont, noobj, cls);
        }
    }

    // ---- wave64 + block reduce, then ONE plain float4 store per block ----
    #pragma unroll
    for (int off = 32; off > 0; off >>= 1) {
        reg   += __shfl_down(reg, off);
        cont  += __shfl_down(cont, off);
        noobj += __shfl_down(noobj, off);
        cls   += __shfl_down(cls, off);
    }

    __shared__ float sred[4][4];
    if (lane == 0) {
        sred[wv][0] = reg; sred[wv][1] = cont;
        sred[wv][2] = noobj; sred[wv][3] = cls;
    }
    __syncthreads();
    if (tid == 0) {
        float r = 0, c = 0, no = 0, cl = 0;
        #pragma unroll
        for (int w = 0; w < 4; ++w) {
            r += sred[w][0]; c += sred[w][1]; no += sred[w][2]; cl += sred[w][3];
        }
        reinterpret_cast<float4*>(ws)[blockIdx.x] = make_float4(r, c, no, cl);
    }
}

__global__ void yolo_finalize_kernel(const float* __restrict__ ws,
                                     float* __restrict__ out, float inv_n,
                                     int nblocks) {
    // 256 threads fold all per-block partial slots (kernel boundary = ordering)
    const int tid = threadIdx.x;
    float r = 0, c = 0, no = 0, cl = 0;
    for (int b = tid; b < nblocks; b += 256) {
        const float4 p = reinterpret_cast<const float4*>(ws)[b];
        r += p.x; c += p.y; no += p.z; cl += p.w;
    }
    #pragma unroll
    for (int off = 32; off > 0; off >>= 1) {
        r  += __shfl_down(r, off);
        c  += __shfl_down(c, off);
        no += __shfl_down(no, off);
        cl += __shfl_down(cl, off);
    }
    __shared__ float sred[4][4];
    const int wv = tid >> 6;
    if ((tid & 63) == 0) {
        sred[wv][0] = r; sred[wv][1] = c; sred[wv][2] = no; sred[wv][3] = cl;
    }
    __syncthreads();
    if (tid == 0) {
        float R = 0, C = 0, NO = 0, CL = 0;
        #pragma unroll
        for (int w = 0; w < 4; ++w) {
            R += sred[w][0]; C += sred[w][1]; NO += sred[w][2]; CL += sred[w][3];
        }
        out[0] = (5.0f * R + 0.5f * NO + C + CL) * inv_n;
        out[1] = R;
        out[2] = C;
        out[3] = NO;
        out[4] = CL;
    }
}

extern "C" void kernel_launch(void* const* d_in, const int* in_sizes, int n_in,
                              void* d_out, int out_size, void* d_ws, size_t ws_size,
                              hipStream_t stream) {
    const float* pred = (const float*)d_in[0];
    const float* tbox = (const float*)d_in[1];
    const float* tcls = (const float*)d_in[2];
    const void*  mask = d_in[3];
    float* ws  = (float*)d_ws;
    float* out = (float*)d_out;

    const int ncells = in_sizes[3];                 // N * S * S
    const int n_img  = ncells / (GS * GS);          // N
    const float inv_n = 1.0f / (float)n_img;

    const int grid = (ncells + CPB - 1) / CPB;      // 1568
    yolo_loss_kernel<<<grid, BLOCK, 0, stream>>>(pred, tbox, tcls, mask, ws, ncells);

    yolo_finalize_kernel<<<1, 256, 0, stream>>>(ws, out, inv_n, grid);
}